// Round 6
// baseline (145.025 us; speedup 1.0000x reference)
//
#include <hip/hip_runtime.h>
#include <hip/hip_bf16.h>

// Problem constants (SelfAttention_773094113877)
#define LSEQ 2048
#define NB   2
#define NH   16
#define HD   64
#define NKT  32                      // LSEQ / 64 key-tiles
// Q is pre-scaled by log2(e)/sqrt(EMBED) in proj; attn uses native exp2.
#define QSCALE 0.04508687049285173f

typedef __attribute__((ext_vector_type(8))) __bf16 bf16x8;
typedef __attribute__((ext_vector_type(4))) __bf16 bf16x4;
typedef __attribute__((ext_vector_type(2))) __bf16 bf16x2;
typedef __attribute__((ext_vector_type(4))) float  f32x4;

// ---------------- mask bit-pack: one wave per 64 keys ----------------
__global__ __launch_bounds__(256)
void pack_mask_kernel(const int* __restrict__ mask,
                      unsigned long long* __restrict__ mbits) {
  size_t gw = ((size_t)blockIdx.x * 256 + threadIdx.x) >> 6;  // word index
  int lane = threadIdx.x & 63;
  int v = mask[gw * 64 + lane];
  unsigned long long b = __ballot(v != 0);
  if (lane == 0) mbits[gw] = b;
}

// ---------------- per-head projection: out[nh][l][d] = x[n][l][h*64+:] @ W.T ----
__global__ __launch_bounds__(256)
void proj_kernel(const float* __restrict__ xv, const float* __restrict__ Wv_,
                 const float* __restrict__ xk, const float* __restrict__ Wk_,
                 const float* __restrict__ xq, const float* __restrict__ Wq_,
                 __bf16* __restrict__ outv, __bf16* __restrict__ outk,
                 __bf16* __restrict__ outq) {
  __shared__ float xs[64 * 68];   // also reused as bf16 [64][72] transpose buffer
  __shared__ float Ws[64 * 68];

  const float* x; const float* W; __bf16* out;
  if (blockIdx.z == 0)      { x = xv; W = Wv_; out = outv; }
  else if (blockIdx.z == 1) { x = xk; W = Wk_; out = outk; }
  else                      { x = xq; W = Wq_; out = outq; }
  const float osc = (blockIdx.z == 2) ? QSCALE : 1.0f;

  const int tid = threadIdx.x;
  const int bx = blockIdx.x;
  const int h  = blockIdx.y;
  const int n  = bx >> 5;
  const int l0 = (bx & 31) << 6;
  const float* xb = x + ((size_t)(n * LSEQ + l0)) * 1024 + h * 64;

#pragma unroll
  for (int r = 0; r < 4; ++r) {
    int idx = tid + r * 256;
    int row = idx >> 4, c4 = (idx & 15) * 4;
    *(float4*)(xs + row * 68 + c4) = *(const float4*)(xb + (size_t)row * 1024 + c4);
    *(float4*)(Ws + row * 68 + c4) = *(const float4*)(W + idx * 4);
  }
  __syncthreads();

  const int m  = tid & 15;
  const int dg = tid >> 4;
  float acc[4][4] = {};
#pragma unroll
  for (int jj = 0; jj < 16; ++jj) {
    float4 xvv[4], wvv[4];
#pragma unroll
    for (int s = 0; s < 4; ++s) xvv[s] = *(const float4*)(xs + (m + 16 * s) * 68 + jj * 4);
#pragma unroll
    for (int i = 0; i < 4; ++i) wvv[i] = *(const float4*)(Ws + (dg + 16 * i) * 68 + jj * 4);
#pragma unroll
    for (int s = 0; s < 4; ++s)
#pragma unroll
      for (int i = 0; i < 4; ++i)
        acc[s][i] += xvv[s].x * wvv[i].x + xvv[s].y * wvv[i].y
                   + xvv[s].z * wvv[i].z + xvv[s].w * wvv[i].w;
  }

  // ---- transpose through LDS, then fully-coalesced bf16x8 stores ----
  __syncthreads();
  __bf16* tb = (__bf16*)xs;            // [64][72] bf16; 144B row = 16B-aligned
#pragma unroll
  for (int s = 0; s < 4; ++s)
#pragma unroll
    for (int i = 0; i < 4; ++i)
      tb[(m + 16 * s) * 72 + dg + 16 * i] = (__bf16)(acc[s][i] * osc);
  __syncthreads();

  const int tok = tid >> 2;
  const int d0  = (tid & 3) * 16;
  bf16x8 c0 = *(const bf16x8*)(tb + tok * 72 + d0);
  bf16x8 c1 = *(const bf16x8*)(tb + tok * 72 + d0 + 8);
  size_t ob = (size_t)(n * NH + h) * LSEQ + l0;
  *(bf16x8*)(out + (ob + tok) * HD + d0)     = c0;
  *(bf16x8*)(out + (ob + tok) * HD + d0 + 8) = c1;
}

// ---------------- fused flash attention ----------------
// grid (32, 32) = 1024 blocks, 256 threads = 4 waves x 16 q-rows (64 rows/block).
// Register-P via key-permuted V columns:
//   PV A-frag slot (ks, k=lhi*8+j) <-> key = (2ks+(j>>2))*16 + lhi*4 + (j&3)
//   kslot(k) = (k&32) + ((k>>2)&3)*8 + ((k>>4)&1)*4 + (k&3)
//   (4 consecutive keys 4kg..4kg+3 -> 4 consecutive kslots: b64 staging writes)
// V swizzle: swzV(d) = (d&7)^((d>>3)&7); K swizzle: swzK(key)=key&7.
// lsum computed by MFMA with B=ones (lands directly in C-layout for epilogue).
__global__ __launch_bounds__(256, 4)
void attn_kernel(const __bf16* __restrict__ Qb, const __bf16* __restrict__ Kb,
                 const __bf16* __restrict__ Vb,
                 const unsigned long long* __restrict__ mbits,
                 float* __restrict__ out) {
  __shared__ __bf16 Ks[2][64 * 64];
  __shared__ __bf16 Vts[2][64 * 64];

  const int tid  = threadIdx.x;
  const int wid  = tid >> 6;
  const int lane = tid & 63;
  const int l15  = lane & 15;
  const int lhi  = lane >> 4;

  // XCD-bijective swizzle: 128 blocks/XCD = 4 heads x 32 q-tiles per XCD
  const int lin = blockIdx.y * 32 + blockIdx.x;    // 0..1023
  const int xcd = lin & 7;
  const int idx = lin >> 3;                        // 0..127
  const int nh  = xcd + ((idx >> 5) << 3);
  const int qt  = idx & 31;
  const int n   = nh >> 4;
  const int h   = nh & 15;
  const int q0  = qt << 6;                         // 64 q-rows per block

  const __bf16* Qg = Qb + ((size_t)nh * LSEQ + q0) * HD;
  const __bf16* Kg = Kb + (size_t)nh * LSEQ * HD;
  const __bf16* Vg = Vb + (size_t)nh * LSEQ * HD;

  // Q in regs: qrow = wid*16 + l15, dims ks*32 + lhi*8..+7 (pre-scaled by QSCALE)
  bf16x8 qf[2];
#pragma unroll
  for (int ks = 0; ks < 2; ++ks)
    qf[ks] = *(const bf16x8*)(Qg + (size_t)(wid * 16 + l15) * HD + ks * 32 + lhi * 8);

  f32x4 o[4] = {};
  f32x4 o_ls = {};                                 // MFMA row-sum accumulator
  const unsigned long long* mrow =
      mbits + ((size_t)n * LSEQ + q0 + wid * 16 + l15) * NKT;

  // ones B-fragment for the lsum MFMA
  bf16x8 onesf;
#pragma unroll
  for (int j = 0; j < 8; ++j) onesf[j] = (__bf16)1.0f;

  // V staging: per wave, kg = lane&15 (keys 4kg..4kg+3), dgw = wid*4+lhi (dims 4dgw..+3)
  const int vkg  = lane & 15;
  const int vdgw = (wid << 2) + lhi;
  const int vslotbase = ((vkg & 8) << 2) + ((vkg & 3) << 3) + ((vkg >> 2 & 1) << 2);
  bf16x4 vv[4];

#define STAGE_K(kt_, buf_)                                                         \
  _Pragma("unroll")                                                                \
  for (int it = 0; it < 2; ++it) {                                                 \
    int chb = wid * 64 + it * 256;                                                 \
    int ch = chb + lane;                                                           \
    int skey = ch >> 3, sdc = ch & 7;                                              \
    const __bf16* src = Kg + (size_t)(kt_) * 4096 + skey * 64 + ((sdc ^ (skey & 7)) << 3); \
    __builtin_amdgcn_global_load_lds(                                              \
        (const __attribute__((address_space(1))) void*)src,                        \
        (__attribute__((address_space(3))) void*)(&Ks[buf_][chb * 8]), 16, 0, 0);  \
  }
#define LOAD_V(kt_)                                                                \
  _Pragma("unroll")                                                                \
  for (int m_ = 0; m_ < 4; ++m_)                                                   \
    vv[m_] = *(const bf16x4*)(Vg + (size_t)(kt_) * 4096 + (vkg * 4 + m_) * HD + vdgw * 4);
#define WRITE_V(buf_)                                                              \
  _Pragma("unroll")                                                                \
  for (int i = 0; i < 4; ++i) {                                                    \
    int d = vdgw * 4 + i;                                                          \
    int swz = (d & 7) ^ ((d >> 3) & 7);                                            \
    bf16x4 pr; pr[0] = vv[0][i]; pr[1] = vv[1][i]; pr[2] = vv[2][i]; pr[3] = vv[3][i]; \
    *(bf16x4*)(&Vts[buf_][d * 64 + (vslotbase ^ (swz << 3))]) = pr;                \
  }

  STAGE_K(0, 0);
  LOAD_V(0);
  WRITE_V(0);
  __syncthreads();

  for (int kt = 0; kt < NKT; ++kt) {
    const int cur = kt & 1;
    const int nxt = cur ^ 1;
    const bool pf = (kt + 1 < NKT);
    unsigned long long w = mrow[kt];
    if (pf) {
      STAGE_K(kt + 1, nxt);
      LOAD_V(kt + 1);
    }

    // ---- S^T = K * Q^T : lane holds S[key=t*16+lhi*4+r][qrow=wid*16+l15] ----
    f32x4 s[4] = {};
#pragma unroll
    for (int ks = 0; ks < 2; ++ks)
#pragma unroll
      for (int t = 0; t < 4; ++t) {
        int key = t * 16 + l15;
        bf16x8 kf = *(const bf16x8*)(
            &Ks[cur][key * 64 + ((ks * 32 + lhi * 8) ^ ((key & 7) << 3))]);
        s[t] = __builtin_amdgcn_mfma_f32_16x16x32_bf16(kf, qf[ks], s[t], 0, 0, 0);
      }

    // ---- mask + exp2 -> register P (A-fragment layout, lane-local) ----
    bf16x8 pa[2];
    unsigned long long wsh = w >> (lhi * 4);
    unsigned shl = (unsigned)wsh;
    unsigned shh = (unsigned)(wsh >> 32);
#pragma unroll
    for (int t = 0; t < 4; ++t) {
      unsigned sh = (t < 2) ? shl : shh;
#pragma unroll
      for (int r = 0; r < 4; ++r) {
        float p = exp2f(s[t][r]);                 // Q pre-scaled: s is log2-domain
        p = ((sh >> ((t & 1) * 16 + r)) & 1u) ? p : 0.f;
        pa[t >> 1][(t & 1) * 4 + r] = (__bf16)p;
      }
    }

    if (pf) { WRITE_V(nxt); }   // V loads arrived under QK's MFMA

    // ---- O += P * V ; lsum += P * ones ----
#pragma unroll
    for (int ks = 0; ks < 2; ++ks) {
#pragma unroll
      for (int t = 0; t < 4; ++t) {
        int d = t * 16 + l15;
        int swz = (d & 7) ^ ((d >> 3) & 7);
        bf16x8 vf = *(const bf16x8*)(
            &Vts[cur][d * 64 + ((ks * 32 + lhi * 8) ^ (swz << 3))]);
        o[t] = __builtin_amdgcn_mfma_f32_16x16x32_bf16(pa[ks], vf, o[t], 0, 0, 0);
      }
      o_ls = __builtin_amdgcn_mfma_f32_16x16x32_bf16(pa[ks], onesf, o_ls, 0, 0, 0);
    }

    __syncthreads();
  }

  // ---- finalize: o_ls[r] = row-sum for qrow=wid*16+lhi*4+r (replicated over l15) ----
  float inv[4];
#pragma unroll
  for (int r = 0; r < 4; ++r)
    inv[r] = 1.f / o_ls[r];
#pragma unroll
  for (int r = 0; r < 4; ++r) {
    size_t ob = ((size_t)n * LSEQ + q0 + wid * 16 + lhi * 4 + r) * 1024 + h * 64 + l15;
#pragma unroll
    for (int t = 0; t < 4; ++t)
      out[ob + t * 16] = o[t][r] * inv[r];
  }
#undef STAGE_K
#undef LOAD_V
#undef WRITE_V
}

extern "C" void kernel_launch(void* const* d_in, const int* in_sizes, int n_in,
                              void* d_out, int out_size, void* d_ws, size_t ws_size,
                              hipStream_t stream) {
  const float* xv   = (const float*)d_in[0];   // values
  const float* xk   = (const float*)d_in[1];   // keys
  const float* xq   = (const float*)d_in[2];   // queries
  const int*   mask = (const int*)d_in[3];
  const float* Wv   = (const float*)d_in[4];
  const float* Wk   = (const float*)d_in[5];
  const float* Wq   = (const float*)d_in[6];
  float* out = (float*)d_out;

  const size_t elems = (size_t)NB * NH * LSEQ * HD;       // 4,194,304
  __bf16* Qw = (__bf16*)d_ws;
  __bf16* Kw = Qw + elems;
  __bf16* Vw = Kw + elems;
  unsigned long long* mb = (unsigned long long*)(Vw + elems);  // 1 MB

  pack_mask_kernel<<<dim3(NB * LSEQ * NKT / 4), 256, 0, stream>>>(mask, mb);
  proj_kernel<<<dim3(64, NH, 3), 256, 0, stream>>>(xv, Wv, xk, Wk, xq, Wq,
                                                   Vw, Kw, Qw);
  attn_kernel<<<dim3(32, 32), 256, 0, stream>>>(Qw, Kw, Vw, mb, out);
}

// Round 7
// 130.726 us; speedup vs baseline: 1.1094x; 1.1094x over previous
//
#include <hip/hip_runtime.h>
#include <hip/hip_bf16.h>

// Problem constants (SelfAttention_773094113877)
#define LSEQ 2048
#define NB   2
#define NH   16
#define HD   64
#define NKT  32                      // LSEQ / 64 key-tiles
// Q is pre-scaled by log2(e)/sqrt(EMBED) in proj; attn uses native exp2.
#define QSCALE 0.04508687049285173f

typedef __attribute__((ext_vector_type(8))) __bf16 bf16x8;
typedef __attribute__((ext_vector_type(4))) __bf16 bf16x4;
typedef __attribute__((ext_vector_type(2))) __bf16 bf16x2;
typedef __attribute__((ext_vector_type(4))) float  f32x4;

// ---------------- mask bit-pack: one wave per 64 keys ----------------
__global__ __launch_bounds__(256)
void pack_mask_kernel(const int* __restrict__ mask,
                      unsigned long long* __restrict__ mbits) {
  size_t gw = ((size_t)blockIdx.x * 256 + threadIdx.x) >> 6;  // word index
  int lane = threadIdx.x & 63;
  int v = mask[gw * 64 + lane];
  unsigned long long b = __ballot(v != 0);
  if (lane == 0) mbits[gw] = b;
}

// ---------------- per-head projection: out[nh][l][d] = x[n][l][h*64+:] @ W.T ----
__global__ __launch_bounds__(256)
void proj_kernel(const float* __restrict__ xv, const float* __restrict__ Wv_,
                 const float* __restrict__ xk, const float* __restrict__ Wk_,
                 const float* __restrict__ xq, const float* __restrict__ Wq_,
                 __bf16* __restrict__ outv, __bf16* __restrict__ outk,
                 __bf16* __restrict__ outq) {
  __shared__ float xs[64 * 68];   // also reused as bf16 [64][72] transpose buffer
  __shared__ float Ws[64 * 68];

  const float* x; const float* W; __bf16* out;
  if (blockIdx.z == 0)      { x = xv; W = Wv_; out = outv; }
  else if (blockIdx.z == 1) { x = xk; W = Wk_; out = outk; }
  else                      { x = xq; W = Wq_; out = outq; }
  const float osc = (blockIdx.z == 2) ? QSCALE : 1.0f;

  const int tid = threadIdx.x;
  const int bx = blockIdx.x;
  const int h  = blockIdx.y;
  const int n  = bx >> 5;
  const int l0 = (bx & 31) << 6;
  const float* xb = x + ((size_t)(n * LSEQ + l0)) * 1024 + h * 64;

#pragma unroll
  for (int r = 0; r < 4; ++r) {
    int idx = tid + r * 256;
    int row = idx >> 4, c4 = (idx & 15) * 4;
    *(float4*)(xs + row * 68 + c4) = *(const float4*)(xb + (size_t)row * 1024 + c4);
    *(float4*)(Ws + row * 68 + c4) = *(const float4*)(W + idx * 4);
  }
  __syncthreads();

  const int m  = tid & 15;
  const int dg = tid >> 4;
  float acc[4][4] = {};
#pragma unroll
  for (int jj = 0; jj < 16; ++jj) {
    float4 xvv[4], wvv[4];
#pragma unroll
    for (int s = 0; s < 4; ++s) xvv[s] = *(const float4*)(xs + (m + 16 * s) * 68 + jj * 4);
#pragma unroll
    for (int i = 0; i < 4; ++i) wvv[i] = *(const float4*)(Ws + (dg + 16 * i) * 68 + jj * 4);
#pragma unroll
    for (int s = 0; s < 4; ++s)
#pragma unroll
      for (int i = 0; i < 4; ++i)
        acc[s][i] += xvv[s].x * wvv[i].x + xvv[s].y * wvv[i].y
                   + xvv[s].z * wvv[i].z + xvv[s].w * wvv[i].w;
  }

  // ---- transpose through LDS, then fully-coalesced bf16x8 stores ----
  __syncthreads();
  __bf16* tb = (__bf16*)xs;            // [64][72] bf16; 144B row = 16B-aligned
#pragma unroll
  for (int s = 0; s < 4; ++s)
#pragma unroll
    for (int i = 0; i < 4; ++i)
      tb[(m + 16 * s) * 72 + dg + 16 * i] = (__bf16)(acc[s][i] * osc);
  __syncthreads();

  const int tok = tid >> 2;
  const int d0  = (tid & 3) * 16;
  bf16x8 c0 = *(const bf16x8*)(tb + tok * 72 + d0);
  bf16x8 c1 = *(const bf16x8*)(tb + tok * 72 + d0 + 8);
  size_t ob = (size_t)(n * NH + h) * LSEQ + l0;
  *(bf16x8*)(out + (ob + tok) * HD + d0)     = c0;
  *(bf16x8*)(out + (ob + tok) * HD + d0 + 8) = c1;
}

// ---------------- fused flash attention ----------------
// grid (16, 32) = 512 blocks, 256 threads = 4 waves x 32 q-rows (128 rows/block).
// Register-P via key-permuted V columns:
//   PV A-frag slot (ks, k=lhi*8+j) <-> key = (2ks+(j>>2))*16 + lhi*4 + (j&3)
//   kslot(k) = (k&32) + ((k>>2)&3)*8 + ((k>>4)&1)*4 + (k&3)
//   (4 consecutive keys 4kg..4kg+3 -> 4 consecutive kslots: b64 staging writes)
// V swizzle: swzV(d) = (d&7)^((d>>3)&7); K swizzle: swzK(key)=key&7.
// lsum via MFMA with B=ones (lands in C-layout; epilogue needs no shuffles).
__global__ __launch_bounds__(256)
void attn_kernel(const __bf16* __restrict__ Qb, const __bf16* __restrict__ Kb,
                 const __bf16* __restrict__ Vb,
                 const unsigned long long* __restrict__ mbits,
                 float* __restrict__ out) {
  __shared__ __bf16 Ks[2][64 * 64];
  __shared__ __bf16 Vts[2][64 * 64];

  const int tid  = threadIdx.x;
  const int wid  = tid >> 6;
  const int lane = tid & 63;
  const int l15  = lane & 15;
  const int lhi  = lane >> 4;

  // XCD-bijective swizzle: 64 blocks/XCD = 4 heads x 16 q-tiles per XCD
  const int lin = blockIdx.y * 16 + blockIdx.x;    // 0..511
  const int xcd = lin & 7;
  const int idx = lin >> 3;                        // 0..63
  const int nh  = xcd + ((idx >> 4) << 3);
  const int qt  = idx & 15;
  const int n   = nh >> 4;
  const int h   = nh & 15;
  const int q0  = qt << 7;                         // 128 q-rows per block

  const __bf16* Qg = Qb + ((size_t)nh * LSEQ + q0) * HD;
  const __bf16* Kg = Kb + (size_t)nh * LSEQ * HD;
  const __bf16* Vg = Vb + (size_t)nh * LSEQ * HD;

  // Q in regs (pre-scaled): qrow = wid*32 + mi*16 + l15, dims ks*32 + lhi*8..+7
  bf16x8 qf[2][2];
#pragma unroll
  for (int mi = 0; mi < 2; ++mi)
#pragma unroll
    for (int ks = 0; ks < 2; ++ks)
      qf[mi][ks] = *(const bf16x8*)(Qg + (size_t)(wid * 32 + mi * 16 + l15) * HD
                                       + ks * 32 + lhi * 8);

  f32x4 o[2][4] = {};
  f32x4 o_ls[2] = {};                              // MFMA row-sum accumulators
  const unsigned long long* mrow0 =
      mbits + ((size_t)n * LSEQ + q0 + wid * 32 + l15) * NKT;
  const unsigned long long* mrow1 = mrow0 + (size_t)16 * NKT;

  // ones B-fragment for the lsum MFMA
  bf16x8 onesf;
#pragma unroll
  for (int j = 0; j < 8; ++j) onesf[j] = (__bf16)1.0f;

  // V staging: kg = lane&15 (keys 4kg..4kg+3), dgw = wid*4+lhi (dims 4dgw..+3)
  const int vkg  = lane & 15;
  const int vdgw = (wid << 2) + lhi;
  const int vslotbase = ((vkg & 8) << 2) + ((vkg & 3) << 3) + (((vkg >> 2) & 1) << 2);
  bf16x4 vv[4];

#define STAGE_K(kt_, buf_)                                                         \
  _Pragma("unroll")                                                                \
  for (int it = 0; it < 2; ++it) {                                                 \
    int chb = wid * 64 + it * 256;                                                 \
    int ch = chb + lane;                                                           \
    int skey = ch >> 3, sdc = ch & 7;                                              \
    const __bf16* src = Kg + (size_t)(kt_) * 4096 + skey * 64 + ((sdc ^ (skey & 7)) << 3); \
    __builtin_amdgcn_global_load_lds(                                              \
        (const __attribute__((address_space(1))) void*)src,                        \
        (__attribute__((address_space(3))) void*)(&Ks[buf_][chb * 8]), 16, 0, 0);  \
  }
#define LOAD_V(kt_)                                                                \
  _Pragma("unroll")                                                                \
  for (int m_ = 0; m_ < 4; ++m_)                                                   \
    vv[m_] = *(const bf16x4*)(Vg + (size_t)(kt_) * 4096 + (vkg * 4 + m_) * HD + vdgw * 4);
#define WRITE_V(buf_)                                                              \
  _Pragma("unroll")                                                                \
  for (int i = 0; i < 4; ++i) {                                                    \
    int d = vdgw * 4 + i;                                                          \
    int swz = (d & 7) ^ ((d >> 3) & 7);                                            \
    bf16x4 pr; pr[0] = vv[0][i]; pr[1] = vv[1][i]; pr[2] = vv[2][i]; pr[3] = vv[3][i]; \
    *(bf16x4*)(&Vts[buf_][d * 64 + (vslotbase ^ (swz << 3))]) = pr;                \
  }

  STAGE_K(0, 0);
  LOAD_V(0);
  WRITE_V(0);
  unsigned long long w0 = mrow0[0];
  unsigned long long w1 = mrow1[0];
  __syncthreads();

  for (int kt = 0; kt < NKT; ++kt) {
    const int cur = kt & 1;
    const int nxt = cur ^ 1;
    const bool pf = (kt + 1 < NKT);
    unsigned long long nw0 = 0, nw1 = 0;
    if (pf) {
      STAGE_K(kt + 1, nxt);
      LOAD_V(kt + 1);
      nw0 = mrow0[kt + 1];           // mask prefetch, covered by QK below
      nw1 = mrow1[kt + 1];
    }

    // ---- S^T = K * Q^T ----
    f32x4 s[2][4] = {};
#pragma unroll
    for (int ks = 0; ks < 2; ++ks)
#pragma unroll
      for (int t = 0; t < 4; ++t) {
        int key = t * 16 + l15;
        bf16x8 kf = *(const bf16x8*)(
            &Ks[cur][key * 64 + ((ks * 32 + lhi * 8) ^ ((key & 7) << 3))]);
        s[0][t] = __builtin_amdgcn_mfma_f32_16x16x32_bf16(kf, qf[0][ks], s[0][t], 0, 0, 0);
        s[1][t] = __builtin_amdgcn_mfma_f32_16x16x32_bf16(kf, qf[1][ks], s[1][t], 0, 0, 0);
      }

    // ---- mask + exp2 -> register P (A-fragment layout; Q pre-scaled) ----
    bf16x8 pa[2][2];
#pragma unroll
    for (int mi = 0; mi < 2; ++mi) {
      unsigned long long w = mi ? w1 : w0;
      unsigned long long wsh = w >> (lhi * 4);
      unsigned shl = (unsigned)wsh;
      unsigned shh = (unsigned)(wsh >> 32);
#pragma unroll
      for (int t = 0; t < 4; ++t) {
        unsigned sh = (t < 2) ? shl : shh;
#pragma unroll
        for (int r = 0; r < 4; ++r) {
          float p = exp2f(s[mi][t][r]);           // log2-domain scores
          p = ((sh >> ((t & 1) * 16 + r)) & 1u) ? p : 0.f;
          pa[mi][t >> 1][(t & 1) * 4 + r] = (__bf16)p;
        }
      }
    }

    if (pf) { WRITE_V(nxt); }   // V loads arrived under QK's MFMA

    // ---- O += P * V ; lsum += P * ones ----
#pragma unroll
    for (int ks = 0; ks < 2; ++ks) {
#pragma unroll
      for (int t = 0; t < 4; ++t) {
        int d = t * 16 + l15;
        int swz = (d & 7) ^ ((d >> 3) & 7);
        bf16x8 vf = *(const bf16x8*)(
            &Vts[cur][d * 64 + ((ks * 32 + lhi * 8) ^ (swz << 3))]);
        o[0][t] = __builtin_amdgcn_mfma_f32_16x16x32_bf16(pa[0][ks], vf, o[0][t], 0, 0, 0);
        o[1][t] = __builtin_amdgcn_mfma_f32_16x16x32_bf16(pa[1][ks], vf, o[1][t], 0, 0, 0);
      }
      o_ls[0] = __builtin_amdgcn_mfma_f32_16x16x32_bf16(pa[0][ks], onesf, o_ls[0], 0, 0, 0);
      o_ls[1] = __builtin_amdgcn_mfma_f32_16x16x32_bf16(pa[1][ks], onesf, o_ls[1], 0, 0, 0);
    }

    w0 = nw0;
    w1 = nw1;
    __syncthreads();
  }

  // ---- finalize: o_ls[mi][r] = row-sum for qrow=wid*32+mi*16+lhi*4+r ----
#pragma unroll
  for (int mi = 0; mi < 2; ++mi) {
    float inv[4];
#pragma unroll
    for (int r = 0; r < 4; ++r)
      inv[r] = 1.f / o_ls[mi][r];
#pragma unroll
    for (int r = 0; r < 4; ++r) {
      size_t ob = ((size_t)n * LSEQ + q0 + wid * 32 + mi * 16 + lhi * 4 + r) * 1024
                + h * 64 + l15;
#pragma unroll
      for (int t = 0; t < 4; ++t)
        out[ob + t * 16] = o[mi][t][r] * inv[r];
    }
  }
#undef STAGE_K
#undef LOAD_V
#undef WRITE_V
}

extern "C" void kernel_launch(void* const* d_in, const int* in_sizes, int n_in,
                              void* d_out, int out_size, void* d_ws, size_t ws_size,
                              hipStream_t stream) {
  const float* xv   = (const float*)d_in[0];   // values
  const float* xk   = (const float*)d_in[1];   // keys
  const float* xq   = (const float*)d_in[2];   // queries
  const int*   mask = (const int*)d_in[3];
  const float* Wv   = (const float*)d_in[4];
  const float* Wk   = (const float*)d_in[5];
  const float* Wq   = (const float*)d_in[6];
  float* out = (float*)d_out;

  const size_t elems = (size_t)NB * NH * LSEQ * HD;       // 4,194,304
  __bf16* Qw = (__bf16*)d_ws;
  __bf16* Kw = Qw + elems;
  __bf16* Vw = Kw + elems;
  unsigned long long* mb = (unsigned long long*)(Vw + elems);  // 1 MB

  pack_mask_kernel<<<dim3(NB * LSEQ * NKT / 4), 256, 0, stream>>>(mask, mb);
  proj_kernel<<<dim3(64, NH, 3), 256, 0, stream>>>(xv, Wv, xk, Wk, xq, Wq,
                                                   Vw, Kw, Qw);
  attn_kernel<<<dim3(16, 32), 256, 0, stream>>>(Qw, Kw, Vw, mb, out);
}

// Round 8
// 104.494 us; speedup vs baseline: 1.3879x; 1.2510x over previous
//
#include <hip/hip_runtime.h>
#include <hip/hip_bf16.h>

// Problem constants (SelfAttention_773094113877)
#define LSEQ 2048
#define NB   2
#define NH   16
#define HD   64
#define NKT  32                      // LSEQ / 64 key-tiles
// Q is pre-scaled by log2(e)/sqrt(EMBED) in proj; attn uses native exp2.
#define QSCALE 0.04508687049285173f

typedef __attribute__((ext_vector_type(8))) __bf16 bf16x8;
typedef __attribute__((ext_vector_type(4))) __bf16 bf16x4;
typedef __attribute__((ext_vector_type(2))) __bf16 bf16x2;
typedef __attribute__((ext_vector_type(4))) float  f32x4;

// ---------------- mask bit-pack: one wave per 64 keys ----------------
__global__ __launch_bounds__(256)
void pack_mask_kernel(const int* __restrict__ mask,
                      unsigned long long* __restrict__ mbits) {
  size_t gw = ((size_t)blockIdx.x * 256 + threadIdx.x) >> 6;  // word index
  int lane = threadIdx.x & 63;
  int v = mask[gw * 64 + lane];
  unsigned long long b = __ballot(v != 0);
  if (lane == 0) mbits[gw] = b;
}

// ---------------- per-head projection via MFMA (bf16 split-3) ----------------
// out[nh][l][d] = x[n][l][h*64+:] @ W.T, numerically ~fp32:
//   x = xh + xl, W = wh + wl (bf16 hi/lo); acc += xh*wh + xh*wl + xl*wh (fp32 acc)
// LDS: Xh/Xl/Wh/Wl [64][64] bf16, XOR-swizzled (elem ^= (row&7)<<3).
// Epilogue: LDS transpose buffer -> coalesced bf16x8 stores.
__global__ __launch_bounds__(256)
void proj_kernel(const float* __restrict__ xv, const float* __restrict__ Wv_,
                 const float* __restrict__ xk, const float* __restrict__ Wk_,
                 const float* __restrict__ xq, const float* __restrict__ Wq_,
                 __bf16* __restrict__ outv, __bf16* __restrict__ outk,
                 __bf16* __restrict__ outq) {
  __shared__ __bf16 S[16384];          // 32 KB: Xh|Xl|Wh|Wl; tb aliases Xh/Xl
  __bf16* Xh = S;
  __bf16* Xl = S + 4096;
  __bf16* Wh = S + 8192;
  __bf16* Wl = S + 12288;

  const float* x; const float* W; __bf16* out;
  if (blockIdx.z == 0)      { x = xv; W = Wv_; out = outv; }
  else if (blockIdx.z == 1) { x = xk; W = Wk_; out = outk; }
  else                      { x = xq; W = Wq_; out = outq; }
  const float osc = (blockIdx.z == 2) ? QSCALE : 1.0f;

  const int tid = threadIdx.x;
  const int bx = blockIdx.x;
  const int h  = blockIdx.y;
  const int n  = bx >> 5;
  const int l0 = (bx & 31) << 6;

  // ---- stage + convert: thread = row r (0..63), col chunk c0 (16 f32) ----
  const int r  = tid >> 2;
  const int c0 = (tid & 3) << 4;
  const float* xrow = x + ((size_t)(n * LSEQ + l0) + r) * 1024 + h * 64 + c0;
  const float* wrow = W + r * 64 + c0;

#pragma unroll
  for (int hf = 0; hf < 2; ++hf) {
    int kc = c0 + hf * 8;
    int off = r * 64 + (kc ^ ((r & 7) << 3));
    float4 a = *(const float4*)(xrow + hf * 8);
    float4 b = *(const float4*)(xrow + hf * 8 + 4);
    float va[8] = {a.x, a.y, a.z, a.w, b.x, b.y, b.z, b.w};
    bf16x8 hi, lo;
#pragma unroll
    for (int j = 0; j < 8; ++j) {
      __bf16 h_ = (__bf16)va[j];
      hi[j] = h_;
      lo[j] = (__bf16)(va[j] - (float)h_);
    }
    *(bf16x8*)(Xh + off) = hi;
    *(bf16x8*)(Xl + off) = lo;

    float4 c = *(const float4*)(wrow + hf * 8);
    float4 d = *(const float4*)(wrow + hf * 8 + 4);
    float vw[8] = {c.x, c.y, c.z, c.w, d.x, d.y, d.z, d.w};
    bf16x8 whv, wlv;
#pragma unroll
    for (int j = 0; j < 8; ++j) {
      __bf16 h_ = (__bf16)vw[j];
      whv[j] = h_;
      wlv[j] = (__bf16)(vw[j] - (float)h_);
    }
    *(bf16x8*)(Wh + off) = whv;
    *(bf16x8*)(Wl + off) = wlv;
  }
  __syncthreads();

  // ---- MFMA: wave wv handles tokens wv*16..+15 x all 64 d_out ----
  const int wv   = tid >> 6;
  const int lane = tid & 63;
  const int l15  = lane & 15;
  const int lhi  = lane >> 4;

  bf16x8 xhf[2], xlf[2];
  const int arow = wv * 16 + l15;
#pragma unroll
  for (int ko = 0; ko < 2; ++ko) {
    int aoff = arow * 64 + ((ko * 32 + lhi * 8) ^ ((arow & 7) << 3));
    xhf[ko] = *(const bf16x8*)(Xh + aoff);
    xlf[ko] = *(const bf16x8*)(Xl + aoff);
  }

  f32x4 acc[4] = {};
#pragma unroll
  for (int cg = 0; cg < 4; ++cg) {
    int d = cg * 16 + l15;
#pragma unroll
    for (int ko = 0; ko < 2; ++ko) {
      int boff = d * 64 + ((ko * 32 + lhi * 8) ^ ((d & 7) << 3));
      bf16x8 whf = *(const bf16x8*)(Wh + boff);
      bf16x8 wlf = *(const bf16x8*)(Wl + boff);
      acc[cg] = __builtin_amdgcn_mfma_f32_16x16x32_bf16(xhf[ko], whf, acc[cg], 0, 0, 0);
      acc[cg] = __builtin_amdgcn_mfma_f32_16x16x32_bf16(xhf[ko], wlf, acc[cg], 0, 0, 0);
      acc[cg] = __builtin_amdgcn_mfma_f32_16x16x32_bf16(xlf[ko], whf, acc[cg], 0, 0, 0);
    }
  }
  __syncthreads();

  // ---- transpose through LDS (alias Xh/Xl region), coalesced stores ----
  __bf16* tb = S;                      // [64][72]
#pragma unroll
  for (int cg = 0; cg < 4; ++cg)
#pragma unroll
    for (int rr = 0; rr < 4; ++rr)
      tb[(wv * 16 + lhi * 4 + rr) * 72 + cg * 16 + l15] = (__bf16)(acc[cg][rr] * osc);
  __syncthreads();

  const int tok = tid >> 2;
  const int d0  = (tid & 3) * 16;
  bf16x8 o0 = *(const bf16x8*)(tb + tok * 72 + d0);
  bf16x8 o1 = *(const bf16x8*)(tb + tok * 72 + d0 + 8);
  size_t ob = (size_t)(n * NH + h) * LSEQ + l0;
  *(bf16x8*)(out + (ob + tok) * HD + d0)     = o0;
  *(bf16x8*)(out + (ob + tok) * HD + d0 + 8) = o1;
}

// ---------------- fused flash attention ----------------
// grid (16, 32) = 512 blocks, 256 threads = 4 waves x 32 q-rows (128 rows/block).
// Register-P via key-permuted V columns:
//   PV A-frag slot (ks, k=lhi*8+j) <-> key = (2ks+(j>>2))*16 + lhi*4 + (j&3)
//   kslot(k) = (k&32) + ((k>>2)&3)*8 + ((k>>4)&1)*4 + (k&3)
// V swizzle: swzV(d) = (d&7)^((d>>3)&7); K swizzle: swzK(key)=key&7.
// lsum via MFMA with B=ones. exp via __builtin_amdgcn_exp2f (raw v_exp_f32).
__global__ __launch_bounds__(256)
void attn_kernel(const __bf16* __restrict__ Qb, const __bf16* __restrict__ Kb,
                 const __bf16* __restrict__ Vb,
                 const unsigned long long* __restrict__ mbits,
                 float* __restrict__ out) {
  __shared__ __bf16 Ks[2][64 * 64];
  __shared__ __bf16 Vts[2][64 * 64];

  const int tid  = threadIdx.x;
  const int wid  = tid >> 6;
  const int lane = tid & 63;
  const int l15  = lane & 15;
  const int lhi  = lane >> 4;

  // XCD-bijective swizzle: 64 blocks/XCD = 4 heads x 16 q-tiles per XCD
  const int lin = blockIdx.y * 16 + blockIdx.x;    // 0..511
  const int xcd = lin & 7;
  const int idx = lin >> 3;                        // 0..63
  const int nh  = xcd + ((idx >> 4) << 3);
  const int qt  = idx & 15;
  const int n   = nh >> 4;
  const int h   = nh & 15;
  const int q0  = qt << 7;                         // 128 q-rows per block

  const __bf16* Qg = Qb + ((size_t)nh * LSEQ + q0) * HD;
  const __bf16* Kg = Kb + (size_t)nh * LSEQ * HD;
  const __bf16* Vg = Vb + (size_t)nh * LSEQ * HD;

  // Q in regs (pre-scaled): qrow = wid*32 + mi*16 + l15, dims ks*32 + lhi*8..+7
  bf16x8 qf[2][2];
#pragma unroll
  for (int mi = 0; mi < 2; ++mi)
#pragma unroll
    for (int ks = 0; ks < 2; ++ks)
      qf[mi][ks] = *(const bf16x8*)(Qg + (size_t)(wid * 32 + mi * 16 + l15) * HD
                                       + ks * 32 + lhi * 8);

  f32x4 o[2][4] = {};
  f32x4 o_ls[2] = {};                              // MFMA row-sum accumulators
  const unsigned long long* mrow0 =
      mbits + ((size_t)n * LSEQ + q0 + wid * 32 + l15) * NKT;
  const unsigned long long* mrow1 = mrow0 + (size_t)16 * NKT;

  // ones B-fragment for the lsum MFMA
  bf16x8 onesf;
#pragma unroll
  for (int j = 0; j < 8; ++j) onesf[j] = (__bf16)1.0f;

  // V staging: kg = lane&15 (keys 4kg..4kg+3), dgw = wid*4+lhi (dims 4dgw..+3)
  const int vkg  = lane & 15;
  const int vdgw = (wid << 2) + lhi;
  const int vslotbase = ((vkg & 8) << 2) + ((vkg & 3) << 3) + (((vkg >> 2) & 1) << 2);
  bf16x4 vv[4];

#define STAGE_K(kt_, buf_)                                                         \
  _Pragma("unroll")                                                                \
  for (int it = 0; it < 2; ++it) {                                                 \
    int chb = wid * 64 + it * 256;                                                 \
    int ch = chb + lane;                                                           \
    int skey = ch >> 3, sdc = ch & 7;                                              \
    const __bf16* src = Kg + (size_t)(kt_) * 4096 + skey * 64 + ((sdc ^ (skey & 7)) << 3); \
    __builtin_amdgcn_global_load_lds(                                              \
        (const __attribute__((address_space(1))) void*)src,                        \
        (__attribute__((address_space(3))) void*)(&Ks[buf_][chb * 8]), 16, 0, 0);  \
  }
#define LOAD_V(kt_)                                                                \
  _Pragma("unroll")                                                                \
  for (int m_ = 0; m_ < 4; ++m_)                                                   \
    vv[m_] = *(const bf16x4*)(Vg + (size_t)(kt_) * 4096 + (vkg * 4 + m_) * HD + vdgw * 4);
#define WRITE_V(buf_)                                                              \
  _Pragma("unroll")                                                                \
  for (int i = 0; i < 4; ++i) {                                                    \
    int d = vdgw * 4 + i;                                                          \
    int swz = (d & 7) ^ ((d >> 3) & 7);                                            \
    bf16x4 pr; pr[0] = vv[0][i]; pr[1] = vv[1][i]; pr[2] = vv[2][i]; pr[3] = vv[3][i]; \
    *(bf16x4*)(&Vts[buf_][d * 64 + (vslotbase ^ (swz << 3))]) = pr;                \
  }

  STAGE_K(0, 0);
  LOAD_V(0);
  WRITE_V(0);
  unsigned long long w0 = mrow0[0];
  unsigned long long w1 = mrow1[0];
  __syncthreads();

  for (int kt = 0; kt < NKT; ++kt) {
    const int cur = kt & 1;
    const int nxt = cur ^ 1;
    const bool pf = (kt + 1 < NKT);
    unsigned long long nw0 = 0, nw1 = 0;
    if (pf) {
      STAGE_K(kt + 1, nxt);
      LOAD_V(kt + 1);
      nw0 = mrow0[kt + 1];           // mask prefetch, covered by QK below
      nw1 = mrow1[kt + 1];
    }

    // ---- S^T = K * Q^T ----
    f32x4 s[2][4] = {};
#pragma unroll
    for (int ks = 0; ks < 2; ++ks)
#pragma unroll
      for (int t = 0; t < 4; ++t) {
        int key = t * 16 + l15;
        bf16x8 kf = *(const bf16x8*)(
            &Ks[cur][key * 64 + ((ks * 32 + lhi * 8) ^ ((key & 7) << 3))]);
        s[0][t] = __builtin_amdgcn_mfma_f32_16x16x32_bf16(kf, qf[0][ks], s[0][t], 0, 0, 0);
        s[1][t] = __builtin_amdgcn_mfma_f32_16x16x32_bf16(kf, qf[1][ks], s[1][t], 0, 0, 0);
      }

    // ---- mask + exp2 -> register P (A-fragment layout; Q pre-scaled) ----
    bf16x8 pa[2][2];
#pragma unroll
    for (int mi = 0; mi < 2; ++mi) {
      unsigned long long w = mi ? w1 : w0;
      unsigned long long wsh = w >> (lhi * 4);
      unsigned shl = (unsigned)wsh;
      unsigned shh = (unsigned)(wsh >> 32);
#pragma unroll
      for (int t = 0; t < 4; ++t) {
        unsigned sh = (t < 2) ? shl : shh;
#pragma unroll
        for (int r = 0; r < 4; ++r) {
          float p = __builtin_amdgcn_exp2f(s[mi][t][r]);   // raw v_exp_f32
          p = ((sh >> ((t & 1) * 16 + r)) & 1u) ? p : 0.f;
          pa[mi][t >> 1][(t & 1) * 4 + r] = (__bf16)p;
        }
      }
    }

    if (pf) { WRITE_V(nxt); }   // V loads arrived under QK's MFMA

    // ---- O += P * V ; lsum += P * ones ----
#pragma unroll
    for (int ks = 0; ks < 2; ++ks) {
#pragma unroll
      for (int t = 0; t < 4; ++t) {
        int d = t * 16 + l15;
        int swz = (d & 7) ^ ((d >> 3) & 7);
        bf16x8 vf = *(const bf16x8*)(
            &Vts[cur][d * 64 + ((ks * 32 + lhi * 8) ^ (swz << 3))]);
        o[0][t] = __builtin_amdgcn_mfma_f32_16x16x32_bf16(pa[0][ks], vf, o[0][t], 0, 0, 0);
        o[1][t] = __builtin_amdgcn_mfma_f32_16x16x32_bf16(pa[1][ks], vf, o[1][t], 0, 0, 0);
      }
      o_ls[0] = __builtin_amdgcn_mfma_f32_16x16x32_bf16(pa[0][ks], onesf, o_ls[0], 0, 0, 0);
      o_ls[1] = __builtin_amdgcn_mfma_f32_16x16x32_bf16(pa[1][ks], onesf, o_ls[1], 0, 0, 0);
    }

    w0 = nw0;
    w1 = nw1;
    __syncthreads();
  }

  // ---- finalize: o_ls[mi][r] = row-sum for qrow=wid*32+mi*16+lhi*4+r ----
#pragma unroll
  for (int mi = 0; mi < 2; ++mi) {
    float inv[4];
#pragma unroll
    for (int r = 0; r < 4; ++r)
      inv[r] = 1.f / o_ls[mi][r];
#pragma unroll
    for (int r = 0; r < 4; ++r) {
      size_t ob = ((size_t)n * LSEQ + q0 + wid * 32 + mi * 16 + lhi * 4 + r) * 1024
                + h * 64 + l15;
#pragma unroll
      for (int t = 0; t < 4; ++t)
        out[ob + t * 16] = o[mi][t][r] * inv[r];
    }
  }
#undef STAGE_K
#undef LOAD_V
#undef WRITE_V
}

extern "C" void kernel_launch(void* const* d_in, const int* in_sizes, int n_in,
                              void* d_out, int out_size, void* d_ws, size_t ws_size,
                              hipStream_t stream) {
  const float* xv   = (const float*)d_in[0];   // values
  const float* xk   = (const float*)d_in[1];   // keys
  const float* xq   = (const float*)d_in[2];   // queries
  const int*   mask = (const int*)d_in[3];
  const float* Wv   = (const float*)d_in[4];
  const float* Wk   = (const float*)d_in[5];
  const float* Wq   = (const float*)d_in[6];
  float* out = (float*)d_out;

  const size_t elems = (size_t)NB * NH * LSEQ * HD;       // 4,194,304
  __bf16* Qw = (__bf16*)d_ws;
  __bf16* Kw = Qw + elems;
  __bf16* Vw = Kw + elems;
  unsigned long long* mb = (unsigned long long*)(Vw + elems);  // 1 MB

  pack_mask_kernel<<<dim3(NB * LSEQ * NKT / 4), 256, 0, stream>>>(mask, mb);
  proj_kernel<<<dim3(64, NH, 3), 256, 0, stream>>>(xv, Wv, xk, Wk, xq, Wq,
                                                   Vw, Kw, Qw);
  attn_kernel<<<dim3(16, 32), 256, 0, stream>>>(Qw, Kw, Vw, mb, out);
}

// Round 9
// 103.144 us; speedup vs baseline: 1.4060x; 1.0131x over previous
//
#include <hip/hip_runtime.h>
#include <hip/hip_bf16.h>

// Problem constants (SelfAttention_773094113877)
#define LSEQ 2048
#define NB   2
#define NH   16
#define HD   64
#define NKT  32                      // LSEQ / 64 key-tiles
// Q is pre-scaled by log2(e)/sqrt(EMBED) in proj; attn uses native exp2.
#define QSCALE 0.04508687049285173f

typedef __attribute__((ext_vector_type(8))) __bf16 bf16x8;
typedef __attribute__((ext_vector_type(4))) __bf16 bf16x4;
typedef __attribute__((ext_vector_type(2))) __bf16 bf16x2;
typedef __attribute__((ext_vector_type(4))) float  f32x4;

// ---------------- mask bit-pack: one wave per 64 keys ----------------
__global__ __launch_bounds__(256)
void pack_mask_kernel(const int* __restrict__ mask,
                      unsigned long long* __restrict__ mbits) {
  size_t gw = ((size_t)blockIdx.x * 256 + threadIdx.x) >> 6;  // word index
  int lane = threadIdx.x & 63;
  int v = mask[gw * 64 + lane];
  unsigned long long b = __ballot(v != 0);
  if (lane == 0) mbits[gw] = b;
}

// ---------------- per-head projection via MFMA (bf16 split-3) ----------------
__global__ __launch_bounds__(256)
void proj_kernel(const float* __restrict__ xv, const float* __restrict__ Wv_,
                 const float* __restrict__ xk, const float* __restrict__ Wk_,
                 const float* __restrict__ xq, const float* __restrict__ Wq_,
                 __bf16* __restrict__ outv, __bf16* __restrict__ outk,
                 __bf16* __restrict__ outq) {
  __shared__ __bf16 S[16384];          // 32 KB: Xh|Xl|Wh|Wl; tb aliases Xh/Xl
  __bf16* Xh = S;
  __bf16* Xl = S + 4096;
  __bf16* Wh = S + 8192;
  __bf16* Wl = S + 12288;

  const float* x; const float* W; __bf16* out;
  if (blockIdx.z == 0)      { x = xv; W = Wv_; out = outv; }
  else if (blockIdx.z == 1) { x = xk; W = Wk_; out = outk; }
  else                      { x = xq; W = Wq_; out = outq; }
  const float osc = (blockIdx.z == 2) ? QSCALE : 1.0f;

  const int tid = threadIdx.x;
  const int bx = blockIdx.x;
  const int h  = blockIdx.y;
  const int n  = bx >> 5;
  const int l0 = (bx & 31) << 6;

  const int r  = tid >> 2;
  const int c0 = (tid & 3) << 4;
  const float* xrow = x + ((size_t)(n * LSEQ + l0) + r) * 1024 + h * 64 + c0;
  const float* wrow = W + r * 64 + c0;

#pragma unroll
  for (int hf = 0; hf < 2; ++hf) {
    int kc = c0 + hf * 8;
    int off = r * 64 + (kc ^ ((r & 7) << 3));
    float4 a = *(const float4*)(xrow + hf * 8);
    float4 b = *(const float4*)(xrow + hf * 8 + 4);
    float va[8] = {a.x, a.y, a.z, a.w, b.x, b.y, b.z, b.w};
    bf16x8 hi, lo;
#pragma unroll
    for (int j = 0; j < 8; ++j) {
      __bf16 h_ = (__bf16)va[j];
      hi[j] = h_;
      lo[j] = (__bf16)(va[j] - (float)h_);
    }
    *(bf16x8*)(Xh + off) = hi;
    *(bf16x8*)(Xl + off) = lo;

    float4 c = *(const float4*)(wrow + hf * 8);
    float4 d = *(const float4*)(wrow + hf * 8 + 4);
    float vw[8] = {c.x, c.y, c.z, c.w, d.x, d.y, d.z, d.w};
    bf16x8 whv, wlv;
#pragma unroll
    for (int j = 0; j < 8; ++j) {
      __bf16 h_ = (__bf16)vw[j];
      whv[j] = h_;
      wlv[j] = (__bf16)(vw[j] - (float)h_);
    }
    *(bf16x8*)(Wh + off) = whv;
    *(bf16x8*)(Wl + off) = wlv;
  }
  __syncthreads();

  const int wv   = tid >> 6;
  const int lane = tid & 63;
  const int l15  = lane & 15;
  const int lhi  = lane >> 4;

  bf16x8 xhf[2], xlf[2];
  const int arow = wv * 16 + l15;
#pragma unroll
  for (int ko = 0; ko < 2; ++ko) {
    int aoff = arow * 64 + ((ko * 32 + lhi * 8) ^ ((arow & 7) << 3));
    xhf[ko] = *(const bf16x8*)(Xh + aoff);
    xlf[ko] = *(const bf16x8*)(Xl + aoff);
  }

  f32x4 acc[4] = {};
#pragma unroll
  for (int cg = 0; cg < 4; ++cg) {
    int d = cg * 16 + l15;
#pragma unroll
    for (int ko = 0; ko < 2; ++ko) {
      int boff = d * 64 + ((ko * 32 + lhi * 8) ^ ((d & 7) << 3));
      bf16x8 whf = *(const bf16x8*)(Wh + boff);
      bf16x8 wlf = *(const bf16x8*)(Wl + boff);
      acc[cg] = __builtin_amdgcn_mfma_f32_16x16x32_bf16(xhf[ko], whf, acc[cg], 0, 0, 0);
      acc[cg] = __builtin_amdgcn_mfma_f32_16x16x32_bf16(xhf[ko], wlf, acc[cg], 0, 0, 0);
      acc[cg] = __builtin_amdgcn_mfma_f32_16x16x32_bf16(xlf[ko], whf, acc[cg], 0, 0, 0);
    }
  }
  __syncthreads();

  __bf16* tb = S;                      // [64][72]
#pragma unroll
  for (int cg = 0; cg < 4; ++cg)
#pragma unroll
    for (int rr = 0; rr < 4; ++rr)
      tb[(wv * 16 + lhi * 4 + rr) * 72 + cg * 16 + l15] = (__bf16)(acc[cg][rr] * osc);
  __syncthreads();

  const int tok = tid >> 2;
  const int d0  = (tid & 3) * 16;
  bf16x8 o0 = *(const bf16x8*)(tb + tok * 72 + d0);
  bf16x8 o1 = *(const bf16x8*)(tb + tok * 72 + d0 + 8);
  size_t ob = (size_t)(n * NH + h) * LSEQ + l0;
  *(bf16x8*)(out + (ob + tok) * HD + d0)     = o0;
  *(bf16x8*)(out + (ob + tok) * HD + d0 + 8) = o1;
}

// ---------------- fused flash attention ----------------
// grid (16, 32) = 512 blocks, 512 threads = 8 waves.
// K-split in block: wave = (hw, wq); hw = key-half of each 64-key tile,
// wq = q-row group (32 rows). Waves hw=0 stage V, hw=1 stage K.
// Register-P via key-permuted V columns (kslot keeps bit5 = key-half):
//   PV A-frag slot (hw, k=lhi*8+j) <-> key = hw*32 + (j>=4)*16 + lhi*4 + (j&3)
//   kslot(k) = (k&32) + ((k>>2)&3)*8 + ((k>>4)&1)*4 + (k&3)
// V swizzle: swzV(d) = (d&7)^((d>>3)&7); K swizzle: swzK(key)=key&7.
// lsum via MFMA with B=ones. exp via __builtin_amdgcn_exp2f.
// Epilogue: hw=1 waves dump partial O/lsum to LDS; hw=0 combine + store.
__global__ __launch_bounds__(512, 4)
void attn_kernel(const __bf16* __restrict__ Qb, const __bf16* __restrict__ Kb,
                 const __bf16* __restrict__ Vb,
                 const unsigned long long* __restrict__ mbits,
                 float* __restrict__ out) {
  __shared__ __bf16 KV[16384];         // Ks[buf]=KV+buf*4096 ; Vts[buf]=KV+8192+buf*4096
  __shared__ float  Ls[128];           // partial lsum exchange

  const int tid  = threadIdx.x;
  const int wid  = tid >> 6;
  const int hw   = wid >> 2;           // key-half (0/1)
  const int wq   = wid & 3;            // q-row group
  const int lane = tid & 63;
  const int l15  = lane & 15;
  const int lhi  = lane >> 4;

  // XCD-bijective swizzle: 64 blocks/XCD = 4 heads x 16 q-tiles per XCD
  const int lin = blockIdx.y * 16 + blockIdx.x;    // 0..511
  const int xcd = lin & 7;
  const int idx = lin >> 3;                        // 0..63
  const int nh  = xcd + ((idx >> 4) << 3);
  const int qt  = idx & 15;
  const int n   = nh >> 4;
  const int h   = nh & 15;
  const int q0  = qt << 7;                         // 128 q-rows per block

  const __bf16* Qg = Qb + ((size_t)nh * LSEQ + q0) * HD;
  const __bf16* Kg = Kb + (size_t)nh * LSEQ * HD;
  const __bf16* Vg = Vb + (size_t)nh * LSEQ * HD;

  // Q in regs (pre-scaled): qrow = wq*32 + mi*16 + l15, dims ks*32 + lhi*8..+7
  bf16x8 qf[2][2];
#pragma unroll
  for (int mi = 0; mi < 2; ++mi)
#pragma unroll
    for (int ks = 0; ks < 2; ++ks)
      qf[mi][ks] = *(const bf16x8*)(Qg + (size_t)(wq * 32 + mi * 16 + l15) * HD
                                       + ks * 32 + lhi * 8);

  f32x4 o[2][4] = {};
  f32x4 o_ls[2] = {};
  const unsigned long long* mrow0 =
      mbits + ((size_t)n * LSEQ + q0 + wq * 32 + l15) * NKT;
  const unsigned long long* mrow1 = mrow0 + (size_t)16 * NKT;

  bf16x8 onesf;
#pragma unroll
  for (int j = 0; j < 8; ++j) onesf[j] = (__bf16)1.0f;

  // V staging (hw==0 waves): kg = lane&15 (keys 4kg..+3), dgw = wq*4+lhi (dims 4dgw..+3)
  const int vkg  = lane & 15;
  const int vdgw = (wq << 2) + lhi;
  const int vslotbase = ((vkg & 8) << 2) + ((vkg & 3) << 3) + (((vkg >> 2) & 1) << 2);
  bf16x4 vv[4];

#define STAGE_K(kt_, buf_)                                                         \
  _Pragma("unroll")                                                                \
  for (int it = 0; it < 2; ++it) {                                                 \
    int chb = wq * 64 + it * 256;                                                  \
    int ch = chb + lane;                                                           \
    int skey = ch >> 3, sdc = ch & 7;                                              \
    const __bf16* src = Kg + (size_t)(kt_) * 4096 + skey * 64 + ((sdc ^ (skey & 7)) << 3); \
    __builtin_amdgcn_global_load_lds(                                              \
        (const __attribute__((address_space(1))) void*)src,                        \
        (__attribute__((address_space(3))) void*)(KV + (buf_) * 4096 + chb * 8), 16, 0, 0); \
  }
#define LOAD_V(kt_)                                                                \
  _Pragma("unroll")                                                                \
  for (int m_ = 0; m_ < 4; ++m_)                                                   \
    vv[m_] = *(const bf16x4*)(Vg + (size_t)(kt_) * 4096 + (vkg * 4 + m_) * HD + vdgw * 4);
#define WRITE_V(buf_)                                                              \
  _Pragma("unroll")                                                                \
  for (int i = 0; i < 4; ++i) {                                                    \
    int d = vdgw * 4 + i;                                                          \
    int swz = (d & 7) ^ ((d >> 3) & 7);                                            \
    bf16x4 pr; pr[0] = vv[0][i]; pr[1] = vv[1][i]; pr[2] = vv[2][i]; pr[3] = vv[3][i]; \
    *(bf16x4*)(KV + 8192 + (buf_) * 4096 + d * 64 + (vslotbase ^ (swz << 3))) = pr; \
  }

  if (hw == 1) { STAGE_K(0, 0); }
  else         { LOAD_V(0); WRITE_V(0); }
  unsigned long long w0 = mrow0[0];
  unsigned long long w1 = mrow1[0];
  __syncthreads();

  for (int kt = 0; kt < NKT; ++kt) {
    const int cur = kt & 1;
    const int nxt = cur ^ 1;
    const bool pf = (kt + 1 < NKT);
    unsigned long long nw0 = 0, nw1 = 0;
    if (pf) {
      if (hw == 1) { STAGE_K(kt + 1, nxt); }
      else         { LOAD_V(kt + 1); }
      nw0 = mrow0[kt + 1];
      nw1 = mrow1[kt + 1];
    }

    // ---- S^T = K * Q^T (this wave's 32-key half) ----
    const __bf16* Kc = KV + cur * 4096;
    f32x4 s[2][2] = {};
#pragma unroll
    for (int ks = 0; ks < 2; ++ks)
#pragma unroll
      for (int t = 0; t < 2; ++t) {
        int key = hw * 32 + t * 16 + l15;
        bf16x8 kf = *(const bf16x8*)(
            Kc + key * 64 + ((ks * 32 + lhi * 8) ^ ((key & 7) << 3)));
        s[0][t] = __builtin_amdgcn_mfma_f32_16x16x32_bf16(kf, qf[0][ks], s[0][t], 0, 0, 0);
        s[1][t] = __builtin_amdgcn_mfma_f32_16x16x32_bf16(kf, qf[1][ks], s[1][t], 0, 0, 0);
      }

    // ---- mask + exp2 -> register P (A-fragment layout; Q pre-scaled) ----
    bf16x8 pa[2];
#pragma unroll
    for (int mi = 0; mi < 2; ++mi) {
      unsigned long long w = mi ? w1 : w0;
      unsigned shl = (unsigned)(w >> (hw * 32 + lhi * 4));
#pragma unroll
      for (int t = 0; t < 2; ++t)
#pragma unroll
        for (int r = 0; r < 4; ++r) {
          float p = __builtin_amdgcn_exp2f(s[mi][t][r]);
          p = ((shl >> (t * 16 + r)) & 1u) ? p : 0.f;
          pa[mi][t * 4 + r] = (__bf16)p;
        }
    }

    if (hw == 0 && pf) { WRITE_V(nxt); }

    // ---- O += P * V (this half's kslot chunk) ; lsum += P * ones ----
    const __bf16* Vc = KV + 8192 + cur * 4096;
#pragma unroll
    for (int t = 0; t < 4; ++t) {
      int d = t * 16 + l15;
      int swz = (d & 7) ^ ((d >> 3) & 7);
      bf16x8 vf = *(const bf16x8*)(
          Vc + d * 64 + ((hw * 32 + lhi * 8) ^ (swz << 3)));
      o[0][t] = __builtin_amdgcn_mfma_f32_16x16x32_bf16(pa[0], vf, o[0][t], 0, 0, 0);
      o[1][t] = __builtin_amdgcn_mfma_f32_16x16x32_bf16(pa[1], vf, o[1][t], 0, 0, 0);
    }
    o_ls[0] = __builtin_amdgcn_mfma_f32_16x16x32_bf16(pa[0], onesf, o_ls[0], 0, 0, 0);
    o_ls[1] = __builtin_amdgcn_mfma_f32_16x16x32_bf16(pa[1], onesf, o_ls[1], 0, 0, 0);

    w0 = nw0;
    w1 = nw1;
    __syncthreads();
  }

  // ---- combine halves: hw=1 dumps partials, hw=0 adds + stores ----
  float* Sf = (float*)KV;              // 8192 floats = 32 KB
  if (hw == 1) {
#pragma unroll
    for (int mi = 0; mi < 2; ++mi) {
#pragma unroll
      for (int t = 0; t < 4; ++t)
        *(f32x4*)&Sf[wq * 2048 + (mi * 4 + t) * 256 + lane * 4] = o[mi][t];
      if (l15 == 0)
        *(f32x4*)&Ls[wq * 32 + mi * 16 + lhi * 4] = o_ls[mi];
    }
  }
  __syncthreads();
  if (hw == 0) {
#pragma unroll
    for (int mi = 0; mi < 2; ++mi) {
      f32x4 pls = *(const f32x4*)&Ls[wq * 32 + mi * 16 + lhi * 4];
      float inv[4];
#pragma unroll
      for (int r = 0; r < 4; ++r)
        inv[r] = 1.f / (o_ls[mi][r] + pls[r]);
#pragma unroll
      for (int t = 0; t < 4; ++t) {
        f32x4 po = *(const f32x4*)&Sf[wq * 2048 + (mi * 4 + t) * 256 + lane * 4];
#pragma unroll
        for (int r = 0; r < 4; ++r) {
          size_t ob = ((size_t)n * LSEQ + q0 + wq * 32 + mi * 16 + lhi * 4 + r) * 1024
                    + h * 64 + t * 16 + l15;
          out[ob] = (o[mi][t][r] + po[r]) * inv[r];
        }
      }
    }
  }
#undef STAGE_K
#undef LOAD_V
#undef WRITE_V
}

extern "C" void kernel_launch(void* const* d_in, const int* in_sizes, int n_in,
                              void* d_out, int out_size, void* d_ws, size_t ws_size,
                              hipStream_t stream) {
  const float* xv   = (const float*)d_in[0];   // values
  const float* xk   = (const float*)d_in[1];   // keys
  const float* xq   = (const float*)d_in[2];   // queries
  const int*   mask = (const int*)d_in[3];
  const float* Wv   = (const float*)d_in[4];
  const float* Wk   = (const float*)d_in[5];
  const float* Wq   = (const float*)d_in[6];
  float* out = (float*)d_out;

  const size_t elems = (size_t)NB * NH * LSEQ * HD;       // 4,194,304
  __bf16* Qw = (__bf16*)d_ws;
  __bf16* Kw = Qw + elems;
  __bf16* Vw = Kw + elems;
  unsigned long long* mb = (unsigned long long*)(Vw + elems);  // 1 MB

  pack_mask_kernel<<<dim3(NB * LSEQ * NKT / 4), 256, 0, stream>>>(mask, mb);
  proj_kernel<<<dim3(64, NH, 3), 256, 0, stream>>>(xv, Wv, xk, Wk, xq, Wq,
                                                   Vw, Kw, Qw);
  attn_kernel<<<dim3(16, 32), 512, 0, stream>>>(Qw, Kw, Vw, mb, out);
}